// Round 3
// baseline (746.472 us; speedup 1.0000x reference)
//
#include <hip/hip_runtime.h>

// Problem constants
#define TOK 4096      // B*S tokens
#define DD  1024      // model dim
#define NE  8         // experts
#define FF  4096      // ffn dim
#define NB  8         // batch
#define SS  512       // seq
#define HROWS 8320    // 8192 token-pairs + per-expert tile padding

typedef unsigned short ushort_t;
typedef __attribute__((ext_vector_type(8))) short bshort8;   // 8 bf16 = 4 VGPRs
typedef __attribute__((ext_vector_type(4))) float floatx4;   // MFMA C/D

__device__ __forceinline__ ushort_t f2bf(float f) {
  unsigned int u = __float_as_uint(f);
  u += 0x7fffu + ((u >> 16) & 1u);
  return (ushort_t)(u >> 16);
}
__device__ __forceinline__ float bf2f(ushort_t h) {
  return __uint_as_float(((unsigned int)h) << 16);
}

// async 16B global->LDS (LDS dest = wave-uniform base + lane*16)
__device__ __forceinline__ void gl_lds16(const ushort_t* g, ushort_t* l) {
  __builtin_amdgcn_global_load_lds(
      (const __attribute__((address_space(1))) unsigned int*)g,
      (__attribute__((address_space(3))) unsigned int*)l, 16, 0, 0);
}

// ---------------------------------------------------------------------------
// fp32 -> bf16 cast
// ---------------------------------------------------------------------------
__global__ __launch_bounds__(256) void k_cast(
    const float* __restrict__ in, ushort_t* __restrict__ out, int n4) {
  int i = blockIdx.x * 256 + threadIdx.x;
  if (i < n4) {
    float4 v = ((const float4*)in)[i];
    ushort4 o;
    o.x = f2bf(v.x); o.y = f2bf(v.y); o.z = f2bf(v.z); o.w = f2bf(v.w);
    ((ushort4*)out)[i] = o;
  }
}

// ---------------------------------------------------------------------------
// Transpose + cast: out[c][r] = bf16(in[r][c]); 64x64 tiles; strides as args
// ---------------------------------------------------------------------------
__global__ __launch_bounds__(256) void k_transpose_cast(
    const float* __restrict__ in, size_t in_estride, int in_rstride,
    ushort_t* __restrict__ out, size_t out_estride, int out_rstride) {
  __shared__ ushort_t t[64][70];
  const float* ib = in + blockIdx.z * in_estride;
  ushort_t* ob = out + blockIdx.z * out_estride;
  const int r0 = blockIdx.y * 64, c0 = blockIdx.x * 64;
  const int tid = threadIdx.x;
  const int lr = tid >> 4, lc4 = (tid & 15) * 4;
#pragma unroll
  for (int it = 0; it < 4; ++it) {
    int r = lr + it * 16;
    float4 v = *(const float4*)&ib[(size_t)(r0 + r) * in_rstride + c0 + lc4];
    t[r][lc4 + 0] = f2bf(v.x);
    t[r][lc4 + 1] = f2bf(v.y);
    t[r][lc4 + 2] = f2bf(v.z);
    t[r][lc4 + 3] = f2bf(v.w);
  }
  __syncthreads();
  const int oc = tid >> 5, od2 = (tid & 31) * 2;
#pragma unroll
  for (int it = 0; it < 8; ++it) {
    int cc = oc + it * 8;
    ushort2 w;
    w.x = t[od2 + 0][cc];
    w.y = t[od2 + 1][cc];
    *(ushort2*)&ob[(size_t)(c0 + cc) * out_rstride + r0 + od2] = w;
  }
}

// ---------------------------------------------------------------------------
// Legacy 128x128 MFMA GEMM (kept for MODE 0: lin = x @ W^T + b).
// Depth-2 pipeline, 3 LDS buffers, counted vmcnt(4).
// ---------------------------------------------------------------------------
template <int MODE>
__global__ __launch_bounds__(256) void k_mfma(
    const ushort_t* __restrict__ A, const ushort_t* __restrict__ Bm,
    const float* __restrict__ bias, ushort_t* __restrict__ Obf,
    float* __restrict__ Of, const int* __restrict__ cnt,
    const int* __restrict__ offs, const int* __restrict__ btok, int f0,
    int accum, int kext, int ast, int ost, size_t bstride) {
  const int gx = gridDim.x, gy = gridDim.y;
  int flat = blockIdx.x + gx * (blockIdx.y + gy * blockIdx.z);
  const int nwg = gx * gy * (int)gridDim.z;
  flat = (flat & 7) * (nwg >> 3) + (flat >> 3);
  const int bx = flat % gx;
  const int t2 = flat / gx;
  const int by = t2 % gy;

  const int m0 = by * 128;
  const int n0 = bx * 128;
  const ushort_t* Bp = Bm;

  __shared__ ushort_t Als[3][128 * 32];
  __shared__ ushort_t Bls[3][128 * 32];

  const int tid = threadIdx.x;
  const int lane = tid & 63;
  const int w = tid >> 6;
  const int wm = (w & 1) * 64, wn = (w >> 1) * 64;
  const int lm = lane & 15, lq = lane >> 4;
  const int sr = lane >> 2;
  const int sg = lane & 3;

  const int r0 = w * 32 + sr;
  const int r1 = r0 + 16;
  const int q = (sg - (r0 >> 1)) & 3;
  const int d0 = r0 * 32 + sg * 8;
  const int d1 = r1 * 32 + sg * 8;
  const ushort_t* sA0 = A + (size_t)(m0 + r0) * ast + q * 8;
  const ushort_t* sA1 = A + (size_t)(m0 + r1) * ast + q * 8;
  const ushort_t* sB0 = Bp + (size_t)(n0 + r0) * kext + q * 8;
  const ushort_t* sB1 = Bp + (size_t)(n0 + r1) * kext + q * 8;

#define STG(bi, kt)                            \
  do {                                         \
    const int ko_ = (kt) << 5;                 \
    gl_lds16(sA0 + ko_, &Als[bi][d0]);         \
    gl_lds16(sA1 + ko_, &Als[bi][d1]);         \
    gl_lds16(sB0 + ko_, &Bls[bi][d0]);         \
    gl_lds16(sB1 + ko_, &Bls[bi][d1]);         \
  } while (0)

  floatx4 zero = {0.f, 0.f, 0.f, 0.f};
  floatx4 acc[4][4];
#pragma unroll
  for (int i = 0; i < 4; ++i)
#pragma unroll
    for (int j = 0; j < 4; ++j) acc[i][j] = zero;

  const int nk = kext >> 5;

  STG(0, 0);
  STG(1, 1);
  asm volatile("s_waitcnt vmcnt(4)" ::: "memory");
  asm volatile("s_barrier" ::: "memory");

  int cur = 0;
  for (int k = 0; k < nk; ++k) {
    const ushort_t* Ab = Als[cur];
    const ushort_t* Bb = Bls[cur];
    bshort8 af[4], bfr[4];
#pragma unroll
    for (int i = 0; i < 4; ++i) {
      int r = wm + i * 16 + lm;
      af[i] = *(const bshort8*)&Ab[r * 32 + (((lq + (r >> 1)) & 3) * 8)];
    }
#pragma unroll
    for (int j = 0; j < 4; ++j) {
      int r = wn + j * 16 + lm;
      bfr[j] = *(const bshort8*)&Bb[r * 32 + (((lq + (r >> 1)) & 3) * 8)];
    }
    int pf = cur + 2; if (pf >= 3) pf -= 3;
    if (k + 2 < nk) STG(pf, k + 2);

    asm volatile("s_waitcnt lgkmcnt(0)" ::: "memory");
    __builtin_amdgcn_sched_barrier(0);

#pragma unroll
    for (int i = 0; i < 4; ++i)
#pragma unroll
      for (int j = 0; j < 4; ++j)
        acc[i][j] = __builtin_amdgcn_mfma_f32_16x16x32_bf16(af[i], bfr[j],
                                                            acc[i][j], 0, 0, 0);

    if (k + 1 < nk) {
      if (k + 2 < nk) {
        asm volatile("s_waitcnt vmcnt(4)" ::: "memory");
      } else {
        asm volatile("s_waitcnt vmcnt(0)" ::: "memory");
      }
      asm volatile("s_barrier" ::: "memory");
    }
    cur += 1; if (cur >= 3) cur -= 3;
  }
#undef STG

#pragma unroll
  for (int i = 0; i < 4; ++i) {
#pragma unroll
    for (int j = 0; j < 4; ++j) {
      int n = wn + j * 16 + lm;
#pragma unroll
      for (int rr = 0; rr < 4; ++rr) {
        int m = wm + i * 16 + lq * 4 + rr;
        float v = acc[i][j][rr];
        int gn = n0 + n;
        v += bias[gn];
        Obf[(size_t)(m0 + m) * DD + gn] = f2bf(v);
      }
    }
  }
}

// ---------------------------------------------------------------------------
// 256-wide 8-phase MFMA GEMM (T3+T4+T5), for the expert GEMMs.
//   BM=256, BK=64, 512 threads = 8 waves (2M x 4N). BN = 256 (MODE1) or
//   128 (MODE2). LDS double-buffered; per K-tile:
//     [phases: ds_read half-frags -> s_barrier -> setprio(1) 16xMFMA]
//     boundary: s_barrier; stage tile t+2 into freed buf; vmcnt(VM)
//     (next tile landed, t+2's VM loads stay in flight); s_barrier.
//   LDS swizzle: chunk ^= (row&7) (16B chunks), applied as inverse-swizzled
//   global source (gl_lds dest stays linear) + swizzled ds_read.
// MODE 1: h = relu(A[gather] @ B^T + b1) -> bf16 Obf rows off+p, stride ost
// MODE 2: ob (+)= A @ B^T (+b2 if !accum) -> fp32 Of rows off+p, stride DD
// ---------------------------------------------------------------------------
template <int MODE, int BN>
__global__ __launch_bounds__(512, 2) void k_mg(
    const ushort_t* __restrict__ A, const ushort_t* __restrict__ Bm,
    const float* __restrict__ bias, ushort_t* __restrict__ Obf,
    float* __restrict__ Of, const int* __restrict__ cnt,
    const int* __restrict__ offs, const int* __restrict__ btok, int f0,
    int accum, int kext, int ast, int ost, size_t bstride) {
  constexpr int NFR = BN / 64;   // n-frags per wave (4 or 2)
  constexpr int NLB = BN / 64;   // B stage lines
  constexpr int VM = 4 + NLB;    // loads per tile (A:4 + B:NLB)

  // XCD-aware bijective swizzle (nwg % 8 == 0 for all launches)
  const int gx = gridDim.x, gy = gridDim.y;
  int flat = blockIdx.x + gx * (blockIdx.y + gy * blockIdx.z);
  const int nwg = gx * gy * (int)gridDim.z;
  flat = (flat & 7) * (nwg >> 3) + (flat >> 3);
  const int bx = flat % gx;
  const int t2 = flat / gx;
  const int by = t2 % gy;
  const int bz = t2 / gy;

  const int e = bz;
  const int c = cnt[e];
  const int off = offs[e];
  if (by * 256 >= c) return;
  const int m0 = by * 256;
  const int n0 = bx * BN;
  const ushort_t* Bp = Bm + (size_t)e * bstride;

  __shared__ ushort_t Als[2][256 * 64];
  __shared__ ushort_t Bls[2][BN * 64];
  __shared__ int ts[256];

  const int tid = threadIdx.x;
  if (tid < 256) {
    int p = m0 + tid;
    int r;
    if (MODE == 1) r = btok[e * TOK + min(p, c - 1)];
    else r = off + min(p, c - 1);
    ts[tid] = r;
  }
  __syncthreads();  // publish ts[]; drains all counters -> clean vmcnt base

  const int lane = tid & 63;
  const int w = tid >> 6;
  const int wmi = w >> 2, wni = w & 3;   // 2M x 4N waves
  const int wm = wmi * 128;
  const int wn = wni * (BN / 4);
  const int lm = lane & 15, lq = lane >> 4;

  // staging: line covers 8 rows per wave; lane -> row lane>>3, chunk lane&7.
  // gl_lds dest is linear (base + lane*16B); source carries the inverse
  // swizzle q = (lane&7) ^ (lane>>3)  [= chunk ^ (row&7)]
  const int srow = lane >> 3;
  const int sq = (lane & 7) ^ srow;
  const ushort_t* sAp[4];
  const ushort_t* sBp[NLB];
#pragma unroll
  for (int i = 0; i < 4; ++i)
    sAp[i] = A + (size_t)ts[i * 64 + w * 8 + srow] * ast + sq * 8;
#pragma unroll
  for (int i = 0; i < NLB; ++i)
    sBp[i] = Bp + (size_t)(n0 + i * 64 + w * 8 + srow) * kext + sq * 8;

#define STAGE(bi, kt)                                                   \
  do {                                                                  \
    const int ko_ = (kt) * 64;                                          \
    _Pragma("unroll") for (int i_ = 0; i_ < 4; ++i_)                    \
        gl_lds16(sAp[i_] + ko_,                                         \
                 &Als[bi][(i_ * 64 + w * 8) * 64 + lane * 8]);          \
    _Pragma("unroll") for (int i_ = 0; i_ < NLB; ++i_)                  \
        gl_lds16(sBp[i_] + ko_,                                         \
                 &Bls[bi][(i_ * 64 + w * 8) * 64 + lane * 8]);          \
  } while (0)

  // phase helpers: swizzled ds_read (chunk c at row r lives at c^(r&7))
#define LDA_(MH)                                                        \
  _Pragma("unroll") for (int f_ = 0; f_ < 4; ++f_) {                    \
    const int r_ = wm + (MH)*64 + f_ * 16 + lm;                         \
    _Pragma("unroll") for (int s_ = 0; s_ < 2; ++s_)                    \
        aF[f_][s_] = *(const bshort8*)&Ab[r_ * 64 +                     \
            (((s_ * 4 + lq) ^ (r_ & 7)) * 8)];                          \
  }
#define LDB_(N0)                                                        \
  _Pragma("unroll") for (int j_ = 0; j_ < 2; ++j_) {                    \
    const int r_ = wn + ((N0) + j_) * 16 + lm;                          \
    _Pragma("unroll") for (int s_ = 0; s_ < 2; ++s_)                    \
        bF[j_][s_] = *(const bshort8*)&Bb[r_ * 64 +                     \
            (((s_ * 4 + lq) ^ (r_ & 7)) * 8)];                          \
  }
#define MM_(MH, N0)                                                     \
  __builtin_amdgcn_s_setprio(1);                                        \
  _Pragma("unroll") for (int f_ = 0; f_ < 4; ++f_)                      \
  _Pragma("unroll") for (int j_ = 0; j_ < 2; ++j_)                      \
  _Pragma("unroll") for (int s_ = 0; s_ < 2; ++s_)                      \
      acc[(MH)*4 + f_][(N0) + j_] = __builtin_amdgcn_mfma_f32_16x16x32_bf16( \
          aF[f_][s_], bF[j_][s_], acc[(MH)*4 + f_][(N0) + j_], 0, 0, 0); \
  __builtin_amdgcn_s_setprio(0);

  floatx4 acc[8][NFR];
#pragma unroll
  for (int i = 0; i < 8; ++i)
#pragma unroll
    for (int j = 0; j < NFR; ++j) acc[i][j] = (floatx4){0.f, 0.f, 0.f, 0.f};

  const int NT = kext / 64;

  // prologue: stage tiles 0 and 1; wait tile 0 only (tile 1 stays in flight)
  STAGE(0, 0);
  STAGE(1, 1);
  if constexpr (VM == 8) asm volatile("s_waitcnt vmcnt(8)" ::: "memory");
  else asm volatile("s_waitcnt vmcnt(6)" ::: "memory");
  __builtin_amdgcn_s_barrier();

  for (int kt = 0; kt < NT; ++kt) {
    const int buf = kt & 1;
    const ushort_t* Ab = Als[buf];
    const ushort_t* Bb = Bls[buf];
    bshort8 aF[4][2], bF[2][2];

    if constexpr (NFR == 4) {
      // Gray-code quadrants: (m0,n0) (m0,n1) (m1,n1) (m1,n0)
      LDA_(0); LDB_(0);
      __builtin_amdgcn_s_barrier();
      MM_(0, 0);
      LDB_(2);
      __builtin_amdgcn_s_barrier();
      MM_(0, 2);
      LDA_(1);
      __builtin_amdgcn_s_barrier();
      MM_(1, 2);
      LDB_(0);
      __builtin_amdgcn_s_barrier();
      MM_(1, 0);
    } else {
      LDA_(0); LDB_(0);
      __builtin_amdgcn_s_barrier();
      MM_(0, 0);
      LDA_(1);
      __builtin_amdgcn_s_barrier();
      MM_(1, 0);
    }

    // tile boundary
    __builtin_amdgcn_s_barrier();           // all reads of buf complete
    if (kt + 2 < NT) STAGE(buf, kt + 2);    // refill freed buffer
    if (kt + 1 < NT) {
      if (kt + 2 < NT) {
        if constexpr (VM == 8) asm volatile("s_waitcnt vmcnt(8)" ::: "memory");
        else asm volatile("s_waitcnt vmcnt(6)" ::: "memory");
      } else {
        asm volatile("s_waitcnt vmcnt(0)" ::: "memory");
      }
      __builtin_amdgcn_s_barrier();         // tile kt+1 visible to all waves
    }
  }
#undef STAGE
#undef LDA_
#undef LDB_
#undef MM_

  // epilogue: C mapping col = lane&15, row = (lane>>4)*4 + reg  [m89-verified]
#pragma unroll
  for (int mf = 0; mf < 8; ++mf) {
#pragma unroll
    for (int nf = 0; nf < NFR; ++nf) {
      const int n = wn + nf * 16 + lm;
#pragma unroll
      for (int rr = 0; rr < 4; ++rr) {
        const int m = wm + mf * 16 + lq * 4 + rr;
        float v = acc[mf][nf][rr];
        const int p = m0 + m;
        if (p < c) {
          const int gn = n0 + n;
          if (MODE == 1) {
            v += bias[(size_t)e * FF + f0 + gn];
            v = fmaxf(v, 0.f);
            Obf[(size_t)(off + p) * ost + gn] = f2bf(v);
          } else {
            if (!accum) v += bias[(size_t)e * DD + gn];
            float* dp = &Of[(size_t)(off + p) * DD + gn];
            if (accum) *dp += v; else *dp = v;
          }
        }
      }
    }
  }
}

// ---------------------------------------------------------------------------
// Phase 1 gate: logits + top-2 + renormalized weights. No atomics.
// ---------------------------------------------------------------------------
__global__ __launch_bounds__(256) void k_logits(
    const ushort_t* __restrict__ lin_bf, const float* __restrict__ Wg,
    int* __restrict__ topi, float* __restrict__ wts) {
  const int wv = threadIdx.x >> 6, lane = threadIdx.x & 63;
  const int t = blockIdx.x * 4 + wv;
  float acc[NE] = {};
  const ushort_t* lr = lin_bf + (size_t)t * DD;
#pragma unroll 4
  for (int d0 = 0; d0 < DD; d0 += 64) {
    float v = bf2f(lr[d0 + lane]);
    const float* wgr = Wg + (size_t)(d0 + lane) * NE;
    float4 g0 = *(const float4*)(wgr);
    float4 g1 = *(const float4*)(wgr + 4);
    acc[0] += v * g0.x; acc[1] += v * g0.y; acc[2] += v * g0.z; acc[3] += v * g0.w;
    acc[4] += v * g1.x; acc[5] += v * g1.y; acc[6] += v * g1.z; acc[7] += v * g1.w;
  }
#pragma unroll
  for (int off = 32; off > 0; off >>= 1) {
#pragma unroll
    for (int e = 0; e < NE; ++e) acc[e] += __shfl_xor(acc[e], off);
  }
  if (lane == 0) {
    int i1 = 0;
#pragma unroll
    for (int e = 1; e < NE; ++e)
      if (acc[e] > acc[i1]) i1 = e;
    int i2 = (i1 == 0) ? 1 : 0;
#pragma unroll
    for (int e = 0; e < NE; ++e)
      if (e != i1 && acc[e] > acc[i2]) i2 = e;
    float r = __expf(acc[i2] - acc[i1]);
    topi[t] = i1 | (i2 << 4);
    wts[2 * t + 0] = 1.0f / (1.0f + r);
    wts[2 * t + 1] = r / (1.0f + r);
  }
}

// ---------------------------------------------------------------------------
// Phase 2 route: single block, deterministic counting-sort of 8192 assignments
// ---------------------------------------------------------------------------
#define RT 512
__global__ __launch_bounds__(RT) void k_route(
    const int* __restrict__ topi, int* __restrict__ cnt, int* __restrict__ offs,
    int* __restrict__ btok, int* __restrict__ eslot) {
  __shared__ int sc[NE][RT + 1];
  __shared__ int tot[NE];
  const int tid = threadIdx.x;
  int lc[NE] = {};
  int my[8];
#pragma unroll
  for (int i = 0; i < 8; ++i) {
    int t = tid * 8 + i;
    int p = topi[t];
    my[i] = p;
    lc[p & 15]++;
    lc[(p >> 4) & 15]++;
  }
#pragma unroll
  for (int e = 0; e < NE; ++e) sc[e][tid] = lc[e];
  __syncthreads();
  if (tid < NE) {
    int s = 0;
    for (int i = 0; i < RT; ++i) { int v = sc[tid][i]; sc[tid][i] = s; s += v; }
    tot[tid] = s;
  }
  __syncthreads();
  if (tid == 0) {
    int s = 0;
    for (int e = 0; e < NE; ++e) { offs[e] = s; cnt[e] = tot[e]; s += tot[e]; }
  }
  __syncthreads();
  int run[NE];
#pragma unroll
  for (int e = 0; e < NE; ++e) run[e] = sc[e][tid];
#pragma unroll
  for (int i = 0; i < 8; ++i) {
    int t = tid * 8 + i, p = my[i];
    int e1 = p & 15, e2 = (p >> 4) & 15;
    int s1 = run[e1]++;
    btok[e1 * TOK + s1] = t;
    eslot[2 * t + 0] = e1 * TOK + s1;
    int s2 = run[e2]++;
    btok[e2 * TOK + s2] = t;
    eslot[2 * t + 1] = e2 * TOK + s2;
  }
}

// ---------------------------------------------------------------------------
// Pool: sent[b][d] = (1/S) * sum_s ( x + w0*ob[gp0] + w1*ob[gp1] )
// ---------------------------------------------------------------------------
__global__ __launch_bounds__(256) void k_pool(
    const float* __restrict__ x, const float* __restrict__ ob,
    const int* __restrict__ offs, const int* __restrict__ eslot,
    const float* __restrict__ wts, float* __restrict__ sent) {
  const int b = blockIdx.y;
  const int d = blockIdx.x * 256 + threadIdx.x;
  const int sc = blockIdx.z;
  float a = 0.f;
  for (int s = sc * 64; s < sc * 64 + 64; ++s) {
    int t = b * SS + s;
    int e0 = eslot[2 * t], e1 = eslot[2 * t + 1];
    int g0 = offs[e0 >> 12] + (e0 & (TOK - 1));
    int g1 = offs[e1 >> 12] + (e1 & (TOK - 1));
    a += x[(size_t)t * DD + d] + wts[2 * t] * ob[(size_t)g0 * DD + d] +
         wts[2 * t + 1] * ob[(size_t)g1 * DD + d];
  }
  atomicAdd(&sent[b * DD + d], a * (1.0f / SS));
}

// ---------------------------------------------------------------------------
// Loss
// ---------------------------------------------------------------------------
__global__ __launch_bounds__(1024) void k_loss(
    const float* __restrict__ sent, const int* __restrict__ y,
    float* __restrict__ out) {
  __shared__ float red[16];
  const int tid = threadIdx.x;
  const int lane = tid & 63, wv = tid >> 6;
  float loss = 0.f;
  for (int b = 0; b < NB; ++b) {
    float v = sent[b * DD + tid];
    float m = v;
#pragma unroll
    for (int off = 32; off > 0; off >>= 1) m = fmaxf(m, __shfl_xor(m, off));
    if (lane == 0) red[wv] = m;
    __syncthreads();
    float m2 = red[0];
#pragma unroll
    for (int w = 1; w < 16; ++w) m2 = fmaxf(m2, red[w]);
    __syncthreads();
    float ex = __expf(v - m2);
#pragma unroll
    for (int off = 32; off > 0; off >>= 1) ex += __shfl_xor(ex, off);
    if (lane == 0) red[wv] = ex;
    __syncthreads();
    if (tid == 0) {
      float se = 0.f;
      for (int w = 0; w < 16; ++w) se += red[w];
      loss += m2 + logf(se) - sent[b * DD + y[b]];
    }
    __syncthreads();
  }
  if (tid == 0) out[0] = loss / NB;
}

// ---------------------------------------------------------------------------
extern "C" void kernel_launch(void* const* d_in, const int* in_sizes, int n_in,
                              void* d_out, int out_size, void* d_ws,
                              size_t ws_size, hipStream_t stream) {
  const float* x  = (const float*)d_in[0];
  const int*   y  = (const int*)d_in[1];
  const float* W  = (const float*)d_in[2];
  const float* bb = (const float*)d_in[3];
  const float* Wg = (const float*)d_in[4];
  const float* w1 = (const float*)d_in[5];
  const float* b1 = (const float*)d_in[6];
  const float* w2 = (const float*)d_in[7];
  const float* b2 = (const float*)d_in[8];
  float* out = (float*)d_out;

  auto need = [](size_t FCr) -> size_t {
    size_t o = 0;
    auto al = [&](size_t b) { o = (o + b + 255) & ~255ull; };
    al((size_t)TOK * DD * 2);           // lin_bf
    al((size_t)TOK * DD * 2);           // x_bf
    al((size_t)DD * DD * 2);            // W_bf
    al((size_t)HROWS * FCr * 2);        // h_bf
    al((size_t)NE * FCr * DD * 2);      // w1t
    al((size_t)NE * DD * FCr * 2);      // w2t
    al((size_t)HROWS * DD * 4);         // ob
    al((size_t)NE * TOK * 4);           // btok
    al(64); al(64);                     // cnt, offs
    al((size_t)TOK * 4);                // topi
    al((size_t)2 * TOK * 4);            // eslot
    al((size_t)2 * TOK * 4);            // wts
    al((size_t)NB * DD * 4);            // sent
    return o;
  };
  const int nchunks = (ws_size >= need(FF)) ? 1 : 4;
  const int FCr = FF / nchunks;

  char* base = (char*)d_ws;
  size_t o = 0;
  auto al = [&](size_t b) -> char* {
    char* p = base + o;
    o = (o + b + 255) & ~255ull;
    return p;
  };
  ushort_t* lin_bf = (ushort_t*)al((size_t)TOK * DD * 2);
  ushort_t* x_bf   = (ushort_t*)al((size_t)TOK * DD * 2);
  ushort_t* W_bf   = (ushort_t*)al((size_t)DD * DD * 2);
  ushort_t* h_bf   = (ushort_t*)al((size_t)HROWS * FCr * 2);
  ushort_t* w1t    = (ushort_t*)al((size_t)NE * FCr * DD * 2);
  ushort_t* w2t    = (ushort_t*)al((size_t)NE * DD * FCr * 2);
  float*    ob     = (float*)al((size_t)HROWS * DD * 4);
  int*      btok   = (int*)al((size_t)NE * TOK * 4);
  int*      cnt    = (int*)al(64);
  int*      offs   = (int*)al(64);
  int*      topi   = (int*)al((size_t)TOK * 4);
  int*      eslot  = (int*)al((size_t)2 * TOK * 4);
  float*    wts    = (float*)al((size_t)2 * TOK * 4);
  float*    sent   = (float*)al((size_t)NB * DD * 4);

  hipMemsetAsync(sent, 0, NB * DD * sizeof(float), stream);

  // cast x, W to bf16
  k_cast<<<TOK * DD / 4 / 256, 256, 0, stream>>>(x, x_bf, TOK * DD / 4);
  k_cast<<<DD * DD / 4 / 256, 256, 0, stream>>>(W, W_bf, DD * DD / 4);

  // lin = x @ W^T + b
  k_mfma<0><<<dim3(DD / 128, TOK / 128), 256, 0, stream>>>(
      x_bf, W_bf, bb, lin_bf, nullptr, nullptr, nullptr, nullptr, 0, 0,
      DD, DD, DD, 0);

  // gate (no atomics) + deterministic routing
  k_logits<<<TOK / 4, 256, 0, stream>>>(lin_bf, Wg, topi, wts);
  k_route<<<1, RT, 0, stream>>>(topi, cnt, offs, btok, eslot);

  // expert FFN
  for (int ci = 0; ci < nchunks; ++ci) {
    int f0 = ci * FCr;
    // w1[:, :, f0:f0+FCr] -> w1t [e][f][d]
    k_transpose_cast<<<dim3(FCr / 64, DD / 64, NE), 256, 0, stream>>>(
        w1 + f0, (size_t)DD * FF, FF, w1t, (size_t)FCr * DD, DD);
    k_mg<1, 256><<<dim3(FCr / 256, TOK / 256, NE), 512, 0, stream>>>(
        lin_bf, w1t, b1, h_bf, nullptr, cnt, offs, btok, f0, 0,
        DD, DD, FCr, (size_t)FCr * DD);
    // w2[:, f0:f0+FCr, :] -> w2t [e][d][f]
    k_transpose_cast<<<dim3(DD / 64, FCr / 64, NE), 256, 0, stream>>>(
        w2 + (size_t)f0 * DD, (size_t)FF * DD, DD, w2t, (size_t)DD * FCr, FCr);
    k_mg<2, 128><<<dim3(DD / 128, TOK / 256, NE), 512, 0, stream>>>(
        h_bf, w2t, b2, nullptr, ob, cnt, offs, btok, f0, ci > 0 ? 1 : 0,
        FCr, FCr, DD, (size_t)DD * FCr);
  }

  // pool + loss
  k_pool<<<dim3(DD / 256, NB, 8), 256, 0, stream>>>(x, ob, offs, eslot, wts,
                                                    sent);
  k_loss<<<1, 1024, 0, stream>>>(sent, y, out);
}

// Round 4
// 599.834 us; speedup vs baseline: 1.2445x; 1.2445x over previous
//
#include <hip/hip_runtime.h>

// Problem constants
#define TOK 4096      // B*S tokens
#define DD  1024      // model dim
#define NE  8         // experts
#define FF  4096      // ffn dim
#define NB  8         // batch
#define SS  512       // seq
#define HROWS 8320    // 8192 token-pairs + per-expert tile padding

typedef unsigned short ushort_t;
typedef __attribute__((ext_vector_type(8))) short bshort8;   // 8 bf16 = 4 VGPRs
typedef __attribute__((ext_vector_type(4))) float floatx4;   // MFMA C/D

__device__ __forceinline__ ushort_t f2bf(float f) {
  unsigned int u = __float_as_uint(f);
  u += 0x7fffu + ((u >> 16) & 1u);
  return (ushort_t)(u >> 16);
}
__device__ __forceinline__ float bf2f(ushort_t h) {
  return __uint_as_float(((unsigned int)h) << 16);
}

// async 16B global->LDS (LDS dest = wave-uniform base + lane*16)
__device__ __forceinline__ void gl_lds16(const ushort_t* g, ushort_t* l) {
  __builtin_amdgcn_global_load_lds(
      (const __attribute__((address_space(1))) unsigned int*)g,
      (__attribute__((address_space(3))) unsigned int*)l, 16, 0, 0);
}

// ---------------------------------------------------------------------------
// fp32 -> bf16 cast
// ---------------------------------------------------------------------------
__global__ __launch_bounds__(256) void k_cast(
    const float* __restrict__ in, ushort_t* __restrict__ out, int n4) {
  int i = blockIdx.x * 256 + threadIdx.x;
  if (i < n4) {
    float4 v = ((const float4*)in)[i];
    ushort4 o;
    o.x = f2bf(v.x); o.y = f2bf(v.y); o.z = f2bf(v.z); o.w = f2bf(v.w);
    ((ushort4*)out)[i] = o;
  }
}

// ---------------------------------------------------------------------------
// Transpose + cast: out[c][r] = bf16(in[r][c]); 64x64 tiles; strides as args
// ---------------------------------------------------------------------------
__global__ __launch_bounds__(256) void k_transpose_cast(
    const float* __restrict__ in, size_t in_estride, int in_rstride,
    ushort_t* __restrict__ out, size_t out_estride, int out_rstride) {
  __shared__ ushort_t t[64][70];
  const float* ib = in + blockIdx.z * in_estride;
  ushort_t* ob = out + blockIdx.z * out_estride;
  const int r0 = blockIdx.y * 64, c0 = blockIdx.x * 64;
  const int tid = threadIdx.x;
  const int lr = tid >> 4, lc4 = (tid & 15) * 4;
#pragma unroll
  for (int it = 0; it < 4; ++it) {
    int r = lr + it * 16;
    float4 v = *(const float4*)&ib[(size_t)(r0 + r) * in_rstride + c0 + lc4];
    t[r][lc4 + 0] = f2bf(v.x);
    t[r][lc4 + 1] = f2bf(v.y);
    t[r][lc4 + 2] = f2bf(v.z);
    t[r][lc4 + 3] = f2bf(v.w);
  }
  __syncthreads();
  const int oc = tid >> 5, od2 = (tid & 31) * 2;
#pragma unroll
  for (int it = 0; it < 8; ++it) {
    int cc = oc + it * 8;
    ushort2 w;
    w.x = t[od2 + 0][cc];
    w.y = t[od2 + 1][cc];
    *(ushort2*)&ob[(size_t)(c0 + cc) * out_rstride + r0 + od2] = w;
  }
}

// ---------------------------------------------------------------------------
// Legacy 128x128 MFMA GEMM (MODE 0: lin = x @ W^T + b).
// Depth-2 pipeline, 3 LDS buffers, counted vmcnt(4).
// ---------------------------------------------------------------------------
__global__ __launch_bounds__(256) void k_mfma0(
    const ushort_t* __restrict__ A, const ushort_t* __restrict__ Bm,
    const float* __restrict__ bias, ushort_t* __restrict__ Obf, int kext) {
  const int gx = gridDim.x, gy = gridDim.y;
  int flat = blockIdx.x + gx * blockIdx.y;
  const int nwg = gx * gy;
  flat = (flat & 7) * (nwg >> 3) + (flat >> 3);
  const int bx = flat % gx;
  const int by = flat / gx;

  const int m0 = by * 128;
  const int n0 = bx * 128;

  __shared__ ushort_t Als[3][128 * 32];
  __shared__ ushort_t Bls[3][128 * 32];

  const int tid = threadIdx.x;
  const int lane = tid & 63;
  const int w = tid >> 6;
  const int wm = (w & 1) * 64, wn = (w >> 1) * 64;
  const int lm = lane & 15, lq = lane >> 4;
  const int sr = lane >> 2;
  const int sg = lane & 3;

  const int r0 = w * 32 + sr;
  const int r1 = r0 + 16;
  const int q = (sg - (r0 >> 1)) & 3;
  const int d0 = r0 * 32 + sg * 8;
  const int d1 = r1 * 32 + sg * 8;
  const ushort_t* sA0 = A + (size_t)(m0 + r0) * kext + q * 8;
  const ushort_t* sA1 = A + (size_t)(m0 + r1) * kext + q * 8;
  const ushort_t* sB0 = Bm + (size_t)(n0 + r0) * kext + q * 8;
  const ushort_t* sB1 = Bm + (size_t)(n0 + r1) * kext + q * 8;

#define STG0(bi, kt)                           \
  do {                                         \
    const int ko_ = (kt) << 5;                 \
    gl_lds16(sA0 + ko_, &Als[bi][d0]);         \
    gl_lds16(sA1 + ko_, &Als[bi][d1]);         \
    gl_lds16(sB0 + ko_, &Bls[bi][d0]);         \
    gl_lds16(sB1 + ko_, &Bls[bi][d1]);         \
  } while (0)

  floatx4 zero = {0.f, 0.f, 0.f, 0.f};
  floatx4 acc[4][4];
#pragma unroll
  for (int i = 0; i < 4; ++i)
#pragma unroll
    for (int j = 0; j < 4; ++j) acc[i][j] = zero;

  const int nk = kext >> 5;

  STG0(0, 0);
  STG0(1, 1);
  asm volatile("s_waitcnt vmcnt(4)" ::: "memory");
  asm volatile("s_barrier" ::: "memory");

  int cur = 0;
  for (int k = 0; k < nk; ++k) {
    const ushort_t* Ab = Als[cur];
    const ushort_t* Bb = Bls[cur];
    bshort8 af[4], bfr[4];
#pragma unroll
    for (int i = 0; i < 4; ++i) {
      int r = wm + i * 16 + lm;
      af[i] = *(const bshort8*)&Ab[r * 32 + (((lq + (r >> 1)) & 3) * 8)];
    }
#pragma unroll
    for (int j = 0; j < 4; ++j) {
      int r = wn + j * 16 + lm;
      bfr[j] = *(const bshort8*)&Bb[r * 32 + (((lq + (r >> 1)) & 3) * 8)];
    }
    int pf = cur + 2; if (pf >= 3) pf -= 3;
    if (k + 2 < nk) STG0(pf, k + 2);

    asm volatile("s_waitcnt lgkmcnt(0)" ::: "memory");
    __builtin_amdgcn_sched_barrier(0);

#pragma unroll
    for (int i = 0; i < 4; ++i)
#pragma unroll
      for (int j = 0; j < 4; ++j)
        acc[i][j] = __builtin_amdgcn_mfma_f32_16x16x32_bf16(af[i], bfr[j],
                                                            acc[i][j], 0, 0, 0);

    if (k + 1 < nk) {
      if (k + 2 < nk) {
        asm volatile("s_waitcnt vmcnt(4)" ::: "memory");
      } else {
        asm volatile("s_waitcnt vmcnt(0)" ::: "memory");
      }
      asm volatile("s_barrier" ::: "memory");
    }
    cur += 1; if (cur >= 3) cur -= 3;
  }
#undef STG0

#pragma unroll
  for (int i = 0; i < 4; ++i) {
#pragma unroll
    for (int j = 0; j < 4; ++j) {
      int n = wn + j * 16 + lm;
#pragma unroll
      for (int rr = 0; rr < 4; ++rr) {
        int m = wm + i * 16 + lq * 4 + rr;
        float v = acc[i][j][rr];
        int gn = n0 + n;
        v += bias[gn];
        Obf[(size_t)(m0 + m) * DD + gn] = f2bf(v);
      }
    }
  }
}

// ---------------------------------------------------------------------------
// Expert MFMA GEMM: BM=256, BN=128, BK=32, 512 threads = 8 waves (4M x 2N).
// Same proven depth-2 / 3-buffer / counted-vmcnt sync skeleton as k_mfma0
// (parameter change only). Loads per tile per wave = 3 -> vmcnt(3).
// LDS = 3*(16KB A + 8KB B) + ts = ~73 KB -> 2 blocks/CU (16 waves).
// MODE 1: h = relu(A[gather] @ B^T + b1) -> bf16 Obf rows off+p, stride ost
// MODE 2: ob (+)= A @ B^T (+b2 if !accum) -> fp32 Of rows off+p, stride DD
// ---------------------------------------------------------------------------
template <int MODE>
__global__ __launch_bounds__(512, 4) void k_mg(
    const ushort_t* __restrict__ A, const ushort_t* __restrict__ Bm,
    const float* __restrict__ bias, ushort_t* __restrict__ Obf,
    float* __restrict__ Of, const int* __restrict__ cnt,
    const int* __restrict__ offs, const int* __restrict__ btok, int f0,
    int accum, int kext, int ast, int ost, size_t bstride) {
  // XCD-aware bijective swizzle (nwg % 8 == 0 for all launches)
  const int gx = gridDim.x, gy = gridDim.y;
  int flat = blockIdx.x + gx * (blockIdx.y + gy * blockIdx.z);
  const int nwg = gx * gy * (int)gridDim.z;
  flat = (flat & 7) * (nwg >> 3) + (flat >> 3);
  const int bx = flat % gx;
  const int t2 = flat / gx;
  const int by = t2 % gy;
  const int bz = t2 / gy;

  const int e = bz;
  const int c = cnt[e];
  const int off = offs[e];
  if (by * 256 >= c) return;
  const int m0 = by * 256;
  const int n0 = bx * 128;
  const ushort_t* Bp = Bm + (size_t)e * bstride;

  __shared__ ushort_t Als[3][256 * 32];
  __shared__ ushort_t Bls[3][128 * 32];
  __shared__ int ts[256];

  const int tid = threadIdx.x;
  if (tid < 256) {
    int p = m0 + tid;
    int r;
    if (MODE == 1) r = btok[e * TOK + min(p, c - 1)];
    else r = off + min(p, c - 1);
    ts[tid] = r;
  }
  __syncthreads();  // publish ts[]; drains all counters -> clean vmcnt base

  const int lane = tid & 63;
  const int w = tid >> 6;
  const int wm = (w >> 1) * 64;   // 4 m-waves
  const int wn = (w & 1) * 64;    // 2 n-waves
  const int lm = lane & 15, lq = lane >> 4;
  const int sr = lane >> 2;       // row within wave's 16-row staging group
  const int sg = lane & 3;        // 16B chunk within row

  // staging rows: A rounds 0/1 cover rows 0-127 / 128-255; B covers 0-127.
  // wave w owns rows w*16..w*16+15 of each round (dest = base + lane*16).
  const int ra0 = w * 16 + sr;
  const int ra1 = 128 + ra0;
  const int q = (sg - (ra0 >> 1)) & 3;  // inverse XOR-swizzle on global side
                                        // (ra1 gives same q: 128>>1 % 4 == 0)
  const int dA0 = ra0 * 32 + sg * 8;
  const int dA1 = ra1 * 32 + sg * 8;
  const ushort_t* sA0 = A + (size_t)ts[ra0] * ast + q * 8;
  const ushort_t* sA1 = A + (size_t)ts[ra1] * ast + q * 8;
  const ushort_t* sB0 = Bp + (size_t)(n0 + ra0) * kext + q * 8;

#define STG(bi, kt)                            \
  do {                                         \
    const int ko_ = (kt) << 5;                 \
    gl_lds16(sA0 + ko_, &Als[bi][dA0]);        \
    gl_lds16(sA1 + ko_, &Als[bi][dA1]);        \
    gl_lds16(sB0 + ko_, &Bls[bi][dA0]);        \
  } while (0)

  floatx4 zero = {0.f, 0.f, 0.f, 0.f};
  floatx4 acc[4][4];
#pragma unroll
  for (int i = 0; i < 4; ++i)
#pragma unroll
    for (int j = 0; j < 4; ++j) acc[i][j] = zero;

  const int nk = kext >> 5;

  STG(0, 0);
  STG(1, 1);
  asm volatile("s_waitcnt vmcnt(3)" ::: "memory");
  asm volatile("s_barrier" ::: "memory");

  int cur = 0;
  for (int k = 0; k < nk; ++k) {
    const ushort_t* Ab = Als[cur];
    const ushort_t* Bb = Bls[cur];
    bshort8 af[4], bfr[4];
#pragma unroll
    for (int i = 0; i < 4; ++i) {
      int r = wm + i * 16 + lm;
      af[i] = *(const bshort8*)&Ab[r * 32 + (((lq + (r >> 1)) & 3) * 8)];
    }
#pragma unroll
    for (int j = 0; j < 4; ++j) {
      int r = wn + j * 16 + lm;
      bfr[j] = *(const bshort8*)&Bb[r * 32 + (((lq + (r >> 1)) & 3) * 8)];
    }
    int pf = cur + 2; if (pf >= 3) pf -= 3;
    if (k + 2 < nk) STG(pf, k + 2);

    asm volatile("s_waitcnt lgkmcnt(0)" ::: "memory");
    __builtin_amdgcn_sched_barrier(0);

#pragma unroll
    for (int i = 0; i < 4; ++i)
#pragma unroll
      for (int j = 0; j < 4; ++j)
        acc[i][j] = __builtin_amdgcn_mfma_f32_16x16x32_bf16(af[i], bfr[j],
                                                            acc[i][j], 0, 0, 0);

    if (k + 1 < nk) {
      if (k + 2 < nk) {
        asm volatile("s_waitcnt vmcnt(3)" ::: "memory");
      } else {
        asm volatile("s_waitcnt vmcnt(0)" ::: "memory");
      }
      asm volatile("s_barrier" ::: "memory");
    }
    cur += 1; if (cur >= 3) cur -= 3;
  }
#undef STG

  // epilogue: C mapping col = lane&15, row = (lane>>4)*4 + reg  [m89-verified]
#pragma unroll
  for (int i = 0; i < 4; ++i) {
#pragma unroll
    for (int j = 0; j < 4; ++j) {
      const int n = wn + j * 16 + lm;
#pragma unroll
      for (int rr = 0; rr < 4; ++rr) {
        const int m = wm + i * 16 + lq * 4 + rr;
        float v = acc[i][j][rr];
        const int p = m0 + m;
        if (p < c) {
          const int gn = n0 + n;
          if (MODE == 1) {
            v += bias[(size_t)e * FF + f0 + gn];
            v = fmaxf(v, 0.f);
            Obf[(size_t)(off + p) * ost + gn] = f2bf(v);
          } else {
            if (!accum) v += bias[(size_t)e * DD + gn];
            float* dp = &Of[(size_t)(off + p) * DD + gn];
            if (accum) *dp += v; else *dp = v;
          }
        }
      }
    }
  }
}

// ---------------------------------------------------------------------------
// Phase 1 gate: logits + top-2 + renormalized weights. No atomics.
// ---------------------------------------------------------------------------
__global__ __launch_bounds__(256) void k_logits(
    const ushort_t* __restrict__ lin_bf, const float* __restrict__ Wg,
    int* __restrict__ topi, float* __restrict__ wts) {
  const int wv = threadIdx.x >> 6, lane = threadIdx.x & 63;
  const int t = blockIdx.x * 4 + wv;
  float acc[NE] = {};
  const ushort_t* lr = lin_bf + (size_t)t * DD;
#pragma unroll 4
  for (int d0 = 0; d0 < DD; d0 += 64) {
    float v = bf2f(lr[d0 + lane]);
    const float* wgr = Wg + (size_t)(d0 + lane) * NE;
    float4 g0 = *(const float4*)(wgr);
    float4 g1 = *(const float4*)(wgr + 4);
    acc[0] += v * g0.x; acc[1] += v * g0.y; acc[2] += v * g0.z; acc[3] += v * g0.w;
    acc[4] += v * g1.x; acc[5] += v * g1.y; acc[6] += v * g1.z; acc[7] += v * g1.w;
  }
#pragma unroll
  for (int off = 32; off > 0; off >>= 1) {
#pragma unroll
    for (int e = 0; e < NE; ++e) acc[e] += __shfl_xor(acc[e], off);
  }
  if (lane == 0) {
    int i1 = 0;
#pragma unroll
    for (int e = 1; e < NE; ++e)
      if (acc[e] > acc[i1]) i1 = e;
    int i2 = (i1 == 0) ? 1 : 0;
#pragma unroll
    for (int e = 0; e < NE; ++e)
      if (e != i1 && acc[e] > acc[i2]) i2 = e;
    float r = __expf(acc[i2] - acc[i1]);
    topi[t] = i1 | (i2 << 4);
    wts[2 * t + 0] = 1.0f / (1.0f + r);
    wts[2 * t + 1] = r / (1.0f + r);
  }
}

// ---------------------------------------------------------------------------
// Phase 2 route: single block, deterministic counting-sort of 8192 assignments
// ---------------------------------------------------------------------------
#define RT 512
__global__ __launch_bounds__(RT) void k_route(
    const int* __restrict__ topi, int* __restrict__ cnt, int* __restrict__ offs,
    int* __restrict__ btok, int* __restrict__ eslot) {
  __shared__ int sc[NE][RT + 1];
  __shared__ int tot[NE];
  const int tid = threadIdx.x;
  int lc[NE] = {};
  int my[8];
#pragma unroll
  for (int i = 0; i < 8; ++i) {
    int t = tid * 8 + i;
    int p = topi[t];
    my[i] = p;
    lc[p & 15]++;
    lc[(p >> 4) & 15]++;
  }
#pragma unroll
  for (int e = 0; e < NE; ++e) sc[e][tid] = lc[e];
  __syncthreads();
  if (tid < NE) {
    int s = 0;
    for (int i = 0; i < RT; ++i) { int v = sc[tid][i]; sc[tid][i] = s; s += v; }
    tot[tid] = s;
  }
  __syncthreads();
  if (tid == 0) {
    int s = 0;
    for (int e = 0; e < NE; ++e) { offs[e] = s; cnt[e] = tot[e]; s += tot[e]; }
  }
  __syncthreads();
  int run[NE];
#pragma unroll
  for (int e = 0; e < NE; ++e) run[e] = sc[e][tid];
#pragma unroll
  for (int i = 0; i < 8; ++i) {
    int t = tid * 8 + i, p = my[i];
    int e1 = p & 15, e2 = (p >> 4) & 15;
    int s1 = run[e1]++;
    btok[e1 * TOK + s1] = t;
    eslot[2 * t + 0] = e1 * TOK + s1;
    int s2 = run[e2]++;
    btok[e2 * TOK + s2] = t;
    eslot[2 * t + 1] = e2 * TOK + s2;
  }
}

// ---------------------------------------------------------------------------
// Pool: sent[b][d] = (1/S) * sum_s ( x + w0*ob[gp0] + w1*ob[gp1] )
// ---------------------------------------------------------------------------
__global__ __launch_bounds__(256) void k_pool(
    const float* __restrict__ x, const float* __restrict__ ob,
    const int* __restrict__ offs, const int* __restrict__ eslot,
    const float* __restrict__ wts, float* __restrict__ sent) {
  const int b = blockIdx.y;
  const int d = blockIdx.x * 256 + threadIdx.x;
  const int sc = blockIdx.z;
  float a = 0.f;
  for (int s = sc * 64; s < sc * 64 + 64; ++s) {
    int t = b * SS + s;
    int e0 = eslot[2 * t], e1 = eslot[2 * t + 1];
    int g0 = offs[e0 >> 12] + (e0 & (TOK - 1));
    int g1 = offs[e1 >> 12] + (e1 & (TOK - 1));
    a += x[(size_t)t * DD + d] + wts[2 * t] * ob[(size_t)g0 * DD + d] +
         wts[2 * t + 1] * ob[(size_t)g1 * DD + d];
  }
  atomicAdd(&sent[b * DD + d], a * (1.0f / SS));
}

// ---------------------------------------------------------------------------
// Loss
// ---------------------------------------------------------------------------
__global__ __launch_bounds__(1024) void k_loss(
    const float* __restrict__ sent, const int* __restrict__ y,
    float* __restrict__ out) {
  __shared__ float red[16];
  const int tid = threadIdx.x;
  const int lane = tid & 63, wv = tid >> 6;
  float loss = 0.f;
  for (int b = 0; b < NB; ++b) {
    float v = sent[b * DD + tid];
    float m = v;
#pragma unroll
    for (int off = 32; off > 0; off >>= 1) m = fmaxf(m, __shfl_xor(m, off));
    if (lane == 0) red[wv] = m;
    __syncthreads();
    float m2 = red[0];
#pragma unroll
    for (int w = 1; w < 16; ++w) m2 = fmaxf(m2, red[w]);
    __syncthreads();
    float ex = __expf(v - m2);
#pragma unroll
    for (int off = 32; off > 0; off >>= 1) ex += __shfl_xor(ex, off);
    if (lane == 0) red[wv] = ex;
    __syncthreads();
    if (tid == 0) {
      float se = 0.f;
      for (int w = 0; w < 16; ++w) se += red[w];
      loss += m2 + logf(se) - sent[b * DD + y[b]];
    }
    __syncthreads();
  }
  if (tid == 0) out[0] = loss / NB;
}

// ---------------------------------------------------------------------------
extern "C" void kernel_launch(void* const* d_in, const int* in_sizes, int n_in,
                              void* d_out, int out_size, void* d_ws,
                              size_t ws_size, hipStream_t stream) {
  const float* x  = (const float*)d_in[0];
  const int*   y  = (const int*)d_in[1];
  const float* W  = (const float*)d_in[2];
  const float* bb = (const float*)d_in[3];
  const float* Wg = (const float*)d_in[4];
  const float* w1 = (const float*)d_in[5];
  const float* b1 = (const float*)d_in[6];
  const float* w2 = (const float*)d_in[7];
  const float* b2 = (const float*)d_in[8];
  float* out = (float*)d_out;

  auto need = [](size_t FCr) -> size_t {
    size_t o = 0;
    auto al = [&](size_t b) { o = (o + b + 255) & ~255ull; };
    al((size_t)TOK * DD * 2);           // lin_bf
    al((size_t)TOK * DD * 2);           // x_bf
    al((size_t)DD * DD * 2);            // W_bf
    al((size_t)HROWS * FCr * 2);        // h_bf
    al((size_t)NE * FCr * DD * 2);      // w1t
    al((size_t)NE * DD * FCr * 2);      // w2t
    al((size_t)HROWS * DD * 4);         // ob
    al((size_t)NE * TOK * 4);           // btok
    al(64); al(64);                     // cnt, offs
    al((size_t)TOK * 4);                // topi
    al((size_t)2 * TOK * 4);            // eslot
    al((size_t)2 * TOK * 4);            // wts
    al((size_t)NB * DD * 4);            // sent
    return o;
  };
  const int nchunks = (ws_size >= need(FF)) ? 1 : 4;
  const int FCr = FF / nchunks;

  char* base = (char*)d_ws;
  size_t o = 0;
  auto al = [&](size_t b) -> char* {
    char* p = base + o;
    o = (o + b + 255) & ~255ull;
    return p;
  };
  ushort_t* lin_bf = (ushort_t*)al((size_t)TOK * DD * 2);
  ushort_t* x_bf   = (ushort_t*)al((size_t)TOK * DD * 2);
  ushort_t* W_bf   = (ushort_t*)al((size_t)DD * DD * 2);
  ushort_t* h_bf   = (ushort_t*)al((size_t)HROWS * FCr * 2);
  ushort_t* w1t    = (ushort_t*)al((size_t)NE * FCr * DD * 2);
  ushort_t* w2t    = (ushort_t*)al((size_t)NE * DD * FCr * 2);
  float*    ob     = (float*)al((size_t)HROWS * DD * 4);
  int*      btok   = (int*)al((size_t)NE * TOK * 4);
  int*      cnt    = (int*)al(64);
  int*      offs   = (int*)al(64);
  int*      topi   = (int*)al((size_t)TOK * 4);
  int*      eslot  = (int*)al((size_t)2 * TOK * 4);
  float*    wts    = (float*)al((size_t)2 * TOK * 4);
  float*    sent   = (float*)al((size_t)NB * DD * 4);

  hipMemsetAsync(sent, 0, NB * DD * sizeof(float), stream);

  // cast x, W to bf16
  k_cast<<<TOK * DD / 4 / 256, 256, 0, stream>>>(x, x_bf, TOK * DD / 4);
  k_cast<<<DD * DD / 4 / 256, 256, 0, stream>>>(W, W_bf, DD * DD / 4);

  // lin = x @ W^T + b
  k_mfma0<<<dim3(DD / 128, TOK / 128), 256, 0, stream>>>(
      x_bf, W_bf, bb, lin_bf, DD);

  // gate (no atomics) + deterministic routing
  k_logits<<<TOK / 4, 256, 0, stream>>>(lin_bf, Wg, topi, wts);
  k_route<<<1, RT, 0, stream>>>(topi, cnt, offs, btok, eslot);

  // expert FFN
  for (int ci = 0; ci < nchunks; ++ci) {
    int f0 = ci * FCr;
    // w1[:, :, f0:f0+FCr] -> w1t [e][f][d]
    k_transpose_cast<<<dim3(FCr / 64, DD / 64, NE), 256, 0, stream>>>(
        w1 + f0, (size_t)DD * FF, FF, w1t, (size_t)FCr * DD, DD);
    k_mg<1><<<dim3(FCr / 128, TOK / 256, NE), 512, 0, stream>>>(
        lin_bf, w1t, b1, h_bf, nullptr, cnt, offs, btok, f0, 0,
        DD, DD, FCr, (size_t)FCr * DD);
    // w2[:, f0:f0+FCr, :] -> w2t [e][d][f]
    k_transpose_cast<<<dim3(DD / 64, FCr / 64, NE), 256, 0, stream>>>(
        w2 + (size_t)f0 * DD, (size_t)FF * DD, DD, w2t, (size_t)DD * FCr, FCr);
    k_mg<2><<<dim3(DD / 128, TOK / 256, NE), 512, 0, stream>>>(
        h_bf, w2t, b2, nullptr, ob, cnt, offs, btok, f0, ci > 0 ? 1 : 0,
        FCr, FCr, DD, (size_t)DD * FCr);
  }

  // pool + loss
  k_pool<<<dim3(DD / 256, NB, 8), 256, 0, stream>>>(x, ob, offs, eslot, wts,
                                                    sent);
  k_loss<<<1, 1024, 0, stream>>>(sent, y, out);
}